// Round 9
// baseline (113.331 us; speedup 1.0000x reference)
//
#include <hip/hip_runtime.h>
#include <stdint.h>

#define N_ROWS   16384
#define IN_DIM   512
#define CB_DIM   16
#define CB_VOCAB 8192

// ---- front geometry
#define PREP_BLOCKS 128                          // CB frags + Pf + part/cnt zero
#define PROJ_BLOCKS 1024                         // 1 row-tile each, 4-wave split-K

// ---- scan geometry (R0/R8's measured-38.7us text, verbatim)
#define N_CT   (CB_VOCAB / 16)                   // 512 code-tiles
#define CODEPARTS 16
#define CT_PER_PART (N_CT / CODEPARTS)           // 32
#define N_ROWGRP 64                              // 256 rows per rowgrp

// ---- workspace layout (bytes), ~3.3 MB
#define WS_OFF_AFA  0                            // A-frag [A1|A2]: 1 MB
#define WS_OFF_AFB  (1u << 20)                   // A-frag [A1|A3]: 1 MB
#define WS_OFF_BHH  (2u << 20)                   // B-frag [B1;B2]: 512 KB
#define WS_OFF_B31  ((2u << 20) + (512u << 10))  // B-frag [B3;B1]: 512 KB
#define WS_OFF_PART (3u << 20)                   // u64[16384]: 128 KB
#define WS_OFF_CNT  ((3u << 20) + (128u << 10))  // u32[64]
#define WS_OFF_PF   ((3u << 20) + (192u << 10))  // P-frags: 3 x 1024 x 16 B = 48 KB

typedef __attribute__((ext_vector_type(8))) short bf16x8;
typedef __attribute__((ext_vector_type(4))) float f32x4;

// monotone float -> uint32 key (order-preserving)
__device__ __forceinline__ unsigned fkey(float f) {
    unsigned u = __float_as_uint(f);
    return (u & 0x80000000u) ? ~u : (u | 0x80000000u);
}

// fp32 -> bf16 bits, round-to-nearest-even
__device__ __forceinline__ unsigned short f2bf(float f) {
    unsigned u = __float_as_uint(f);
    return (unsigned short)((u + 0x7FFFu + ((u >> 16) & 1u)) >> 16);
}
__device__ __forceinline__ float bf2f(unsigned short h) {
    return __uint_as_float(((unsigned)h) << 16);
}

// ---------------- K0: prep — zero part/cnt, CB B-frags, P B-frags ----------
// R4's proven text. P-frag layout: level L in {0,1,2}, chunk c in [0,16)
// covers k in [c*32, c*32+32). Frag lane l: n = l&15, k = c*32 + (l>>4)*8+j.
__global__ __launch_bounds__(256, 2)
void k_prep(const float* __restrict__ P, const float* __restrict__ CB,
            bf16x8* __restrict__ Bhh, bf16x8* __restrict__ B31,
            bf16x8* __restrict__ Pf,
            unsigned long long* __restrict__ part, unsigned* __restrict__ cnt) {
    const int pb   = blockIdx.x;
    const int wave = threadIdx.x >> 6;
    const int lane = threadIdx.x & 63;

    if (threadIdx.x < 128) part[pb * 128 + threadIdx.x] = 0ull;
    if (pb == 0 && threadIdx.x < 64) cnt[threadIdx.x] = 0u;

    // ---- CB B-frags (RNE split, unchanged numerics) ----
    {
        const int ct   = pb * 4 + wave;
        const int n    = lane & 15;
        const int quad = lane >> 4;
        const int kh   = (quad & 1) * 8;
        const int lvl  = quad >> 1;
        const int code = ct * 16 + n;

        const float4* b4 = (const float4*)(CB + (size_t)code * CB_DIM + kh);
        float4 a = b4[0], b = b4[1];
        float v[8] = {a.x, a.y, a.z, a.w, b.x, b.y, b.z, b.w};

        bf16x8 shh, s31;
#pragma unroll
        for (int j = 0; j < 8; ++j) {
            float f = v[j];
            unsigned short b1 = f2bf(f);  float r1 = f - bf2f(b1);
            unsigned short b2 = f2bf(r1); float r2 = r1 - bf2f(b2);
            unsigned short b3 = f2bf(r2);
            shh[j] = (short)(lvl ? b2 : b1);
            s31[j] = (short)(lvl ? b1 : b3);
        }
        Bhh[(size_t)ct * 64 + lane] = shh;
        B31[(size_t)ct * 64 + lane] = s31;
    }

    // ---- P B-frags: 1024 frag-lane slots, built by blocks 0..3 (RNE) ----
    const int gslot = pb * 256 + threadIdx.x;
    if (gslot < 1024) {
        const int c  = gslot >> 6;
        const int l  = gslot & 63;
        const int n  = l & 15;
        const int kq = l >> 4;
        const int k0 = c * 32 + kq * 8;

        bf16x8 p1, p2, p3;
#pragma unroll
        for (int j = 0; j < 8; ++j) {
            float f = P[(size_t)(k0 + j) * CB_DIM + n];
            unsigned short b1 = f2bf(f);  float r1 = f - bf2f(b1);
            unsigned short b2 = f2bf(r1); float r2 = r1 - bf2f(b2);
            unsigned short b3 = f2bf(r2);
            p1[j] = (short)b1; p2[j] = (short)b2; p3[j] = (short)b3;
        }
        Pf[gslot]        = p1;
        Pf[1024 + gslot] = p2;
        Pf[2048 + gslot] = p3;
    }
}

// ---------------- K1: MFMA projection, lean ---------------------------------
// R8 ledger: front_splitK was ~30 us (not the assumed 10) and scan 38.7 --
// the FRONT is the pig. Two causes fixed here: (1) Phase A rebuilt the 48 KB
// P-frag table in every block and its LDS capped occupancy at 3 blocks/CU ->
// Pf now read from GLOBAL (48 KB, L2-hot; built once in k_prep), LDS is 4 KB
// fold only -> all 4 blocks/CU resident (16 waves/CU); (2) the RNE 3-way
// split cost ~19 VALU ops/value (hot path: 128 splits/wave) -> TRUNCATE
// split: mask mantissa fields, f == a1+a2+a3 EXACTLY (f 24-bit significand
// -> 8+8+8; each residual subtraction exact), 7 ops/value. Decomposition
// error is zero (RNE-split's was ~2^-25), product/accum error class
// unchanged (~2^-24). Depth-1 named Pf prefetch (rule 20), body ~160 cyc vs
// ~200 cyc L2 latency + 4 waves/SIMD.
__global__ __launch_bounds__(256, 4)
void k_proj(const float* __restrict__ x, const bf16x8* __restrict__ Pf,
            bf16x8* __restrict__ AfragA, bf16x8* __restrict__ AfragB) {
    __shared__ __align__(16) float foldb[1024];  // split-K fold / transpose: 4 KB

    const int tid  = threadIdx.x;
    const int wave = tid >> 6;
    const int lane = tid & 63;
    const int rt   = blockIdx.x;
    const int m    = lane & 15;
    const int kq   = lane >> 4;

    const float4* xr = (const float4*)(x + (size_t)(rt * 16 + m) * IN_DIM);

    float4 xf[8];                                // all 8 x-loads issued upfront
#pragma unroll
    for (int i = 0; i < 4; ++i) {
        xf[2 * i]     = xr[(wave * 4 + i) * 8 + kq * 2];
        xf[2 * i + 1] = xr[(wave * 4 + i) * 8 + kq * 2 + 1];
    }

    f32x4 acc1 = {0.f, 0.f, 0.f, 0.f};
    f32x4 acc2 = {0.f, 0.f, 0.f, 0.f};

    const int c0 = wave * 4;
    // depth-1 named prefetch of the Pf triple
    bf16x8 p1 = Pf[c0 * 64 + lane];
    bf16x8 p2 = Pf[1024 + c0 * 64 + lane];
    bf16x8 p3 = Pf[2048 + c0 * 64 + lane];

#pragma unroll
    for (int i = 0; i < 4; ++i) {
        bf16x8 q1, q2, q3;
        if (i < 3) {
            const int cn = c0 + i + 1;
            q1 = Pf[cn * 64 + lane];
            q2 = Pf[1024 + cn * 64 + lane];
            q3 = Pf[2048 + cn * 64 + lane];
        }

        float4 xa = xf[2 * i], xb = xf[2 * i + 1];
        float xs[8] = {xa.x, xa.y, xa.z, xa.w, xb.x, xb.y, xb.z, xb.w};
        bf16x8 a1, a2, a3;
#pragma unroll
        for (int j = 0; j < 8; ++j) {
            // truncate split: exact f = a1 + a2 + a3 (8+8+8 mantissa bits)
            float f = xs[j];
            unsigned u  = __float_as_uint(f);
            unsigned h1 = u & 0xFFFF0000u;
            float r1 = f - __uint_as_float(h1);
            unsigned u2 = __float_as_uint(r1);
            unsigned h2 = u2 & 0xFFFF0000u;
            float r2 = r1 - __uint_as_float(h2);
            a1[j] = (short)(h1 >> 16);
            a2[j] = (short)(u2 >> 16);
            a3[j] = (short)(__float_as_uint(r2) >> 16);
        }

        // terms i+j<=4: (1,1)(2,1)(2,2) chain1; (1,2)(1,3)(3,1) chain2
        acc1 = __builtin_amdgcn_mfma_f32_16x16x32_bf16(a1, p1, acc1, 0, 0, 0);
        acc2 = __builtin_amdgcn_mfma_f32_16x16x32_bf16(a1, p2, acc2, 0, 0, 0);
        acc1 = __builtin_amdgcn_mfma_f32_16x16x32_bf16(a2, p1, acc1, 0, 0, 0);
        acc2 = __builtin_amdgcn_mfma_f32_16x16x32_bf16(a1, p3, acc2, 0, 0, 0);
        acc1 = __builtin_amdgcn_mfma_f32_16x16x32_bf16(a2, p2, acc1, 0, 0, 0);
        acc2 = __builtin_amdgcn_mfma_f32_16x16x32_bf16(a3, p1, acc2, 0, 0, 0);

        if (i < 3) { p1 = q1; p2 = q2; p3 = q3; }
    }

    *(f32x4*)&foldb[(wave * 64 + lane) * 4] = acc1 + acc2;
    __syncthreads();

    // ---- epilogue (wave 0): fold partials, transpose, split, store ----
    if (wave == 0) {
        f32x4 s0 = *(const f32x4*)&foldb[(0 * 64 + lane) * 4];
        f32x4 s1 = *(const f32x4*)&foldb[(1 * 64 + lane) * 4];
        f32x4 s2 = *(const f32x4*)&foldb[(2 * 64 + lane) * 4];
        f32x4 s3 = *(const f32x4*)&foldb[(3 * 64 + lane) * 4];
        f32x4 sum = ((s0 + s1) + s2) + s3;

        // reads must retire before we overwrite foldb (rule 18 fence)
        asm volatile("s_waitcnt lgkmcnt(0)" ::: "memory");
        __builtin_amdgcn_sched_barrier(0);

        // C layout: lane holds xp[row=(kq*4+r)][col=m] -> transpose [16][20]
#pragma unroll
        for (int r = 0; r < 4; ++r)
            foldb[(kq * 4 + r) * 20 + m] = sum[r];

        asm volatile("s_waitcnt lgkmcnt(0)" ::: "memory");
        __builtin_amdgcn_sched_barrier(0);

        const int kh  = (kq & 1) * 8;
        const int lvl = kq >> 1;
        bf16x8 sa, sb;
#pragma unroll
        for (int j = 0; j < 8; ++j) {
            float f = foldb[m * 20 + kh + j];
            unsigned short b1 = f2bf(f);  float r1 = f - bf2f(b1);
            unsigned short b2 = f2bf(r1); float r2 = r1 - bf2f(b2);
            unsigned short b3 = f2bf(r2);
            sa[j] = (short)(lvl ? b2 : b1);
            sb[j] = (short)(lvl ? b3 : b1);
        }
        AfragA[(size_t)rt * 64 + lane] = sa;
        AfragB[(size_t)rt * 64 + lane] = sb;
    }
}

// ---------------- K2: MFMA sim + argmax + last-block finalize ---------------
// BYTE-IDENTICAL to R8 (measured 38.7 us; issue-port-saturation model says
// it's near its structural floor at this instruction mix -- leave it alone
// this round; attribution stays clean).
__global__ __launch_bounds__(256, 4)
void k_scan(const bf16x8* __restrict__ AfragA, const bf16x8* __restrict__ AfragB,
            const bf16x8* __restrict__ Bhh, const bf16x8* __restrict__ B31,
            unsigned long long* __restrict__ part, unsigned* __restrict__ cnt,
            int* __restrict__ out) {
    __shared__ int s_done;
    const int codepart = blockIdx.x & (CODEPARTS - 1);
    const int rowgrp   = blockIdx.x >> 4;
    const int wave     = threadIdx.x >> 6;
    const int lane     = threadIdx.x & 63;
    const int n        = lane & 15;
    const int quad     = lane >> 4;
    const int rt_base  = rowgrp * 16 + wave * 4;

    bf16x8 Aa[4], Ab[4];
#pragma unroll
    for (int t = 0; t < 4; ++t) {
        Aa[t] = AfragA[(size_t)(rt_base + t) * 64 + lane];
        Ab[t] = AfragB[(size_t)(rt_base + t) * 64 + lane];
    }

    float bestv[4][4];
    int   bestc[4][4];
#pragma unroll
    for (int t = 0; t < 4; ++t)
#pragma unroll
        for (int r = 0; r < 4; ++r) { bestv[t][r] = -INFINITY; bestc[t][r] = 0; }

    const int ct0 = codepart * CT_PER_PART;
    size_t ib = (size_t)ct0 * 64;
    bf16x8 nb1  = Bhh[ib + lane];
    bf16x8 nb1s = Bhh[ib + (lane ^ 32)];
    bf16x8 nb3  = B31[ib + lane];

    for (int c = 0; c < CT_PER_PART; ++c) {
        bf16x8 b1 = nb1, b1s = nb1s, b3 = nb3;
        if (c + 1 < CT_PER_PART) {
            size_t ibn = (size_t)(ct0 + c + 1) * 64;
            nb1  = Bhh[ibn + lane];
            nb1s = Bhh[ibn + (lane ^ 32)];
            nb3  = B31[ibn + lane];
        }
#pragma unroll
        for (int t = 0; t < 4; ++t) {
            f32x4 s = __builtin_amdgcn_mfma_f32_16x16x32_bf16(
                          Aa[t], b1, (f32x4){0.f, 0.f, 0.f, 0.f}, 0, 0, 0);
            s = __builtin_amdgcn_mfma_f32_16x16x32_bf16(Aa[t], b1s, s, 0, 0, 0);
            s = __builtin_amdgcn_mfma_f32_16x16x32_bf16(Ab[t], b3,  s, 0, 0, 0);
#pragma unroll
            for (int r = 0; r < 4; ++r) {
                if (s[r] > bestv[t][r]) { bestv[t][r] = s[r]; bestc[t][r] = c; }
            }
        }
    }

    // reduce over the 16 code-class lanes, then device-scope max per row
#pragma unroll
    for (int t = 0; t < 4; ++t) {
#pragma unroll
        for (int r = 0; r < 4; ++r) {
            unsigned code = (unsigned)(codepart * 512 + bestc[t][r] * 16 + n);
            unsigned long long packed =
                ((unsigned long long)fkey(bestv[t][r]) << 32) |
                (unsigned long long)(0xFFFFFFFFu - code);
#pragma unroll
            for (int mk = 1; mk <= 8; mk <<= 1) {
                unsigned long long o = __shfl_xor(packed, mk, 64);
                packed = (o > packed) ? o : packed;
            }
            if (n == 0) {
                int row = (rt_base + t) * 16 + quad * 4 + r;
                atomicMax(&part[row], packed);
            }
        }
    }

    // __syncthreads drains vmcnt -> all this block's atomics are complete
    __syncthreads();
    if (threadIdx.x == 0)
        s_done = (atomicAdd(&cnt[rowgrp], 1u) == (unsigned)(CODEPARTS - 1));
    __syncthreads();

    if (s_done) {
        int row = rowgrp * 256 + threadIdx.x;
        unsigned long long v = atomicAdd(&part[row], 0ull);   // coherent read
        out[row] = (int)(0xFFFFFFFFu - (unsigned)(v & 0xFFFFFFFFull));
    }
}

extern "C" void kernel_launch(void* const* d_in, const int* in_sizes, int n_in,
                              void* d_out, int out_size, void* d_ws, size_t ws_size,
                              hipStream_t stream) {
    const float* x  = (const float*)d_in[0];   // [16384, 512]
    const float* P  = (const float*)d_in[1];   // [512, 16]
    const float* CB = (const float*)d_in[2];   // [8192, 16]
    int* out = (int*)d_out;                    // [16384] int32

    char* ws = (char*)d_ws;
    bf16x8* AfragA = (bf16x8*)(ws + WS_OFF_AFA);
    bf16x8* AfragB = (bf16x8*)(ws + WS_OFF_AFB);
    bf16x8* Bhh    = (bf16x8*)(ws + WS_OFF_BHH);
    bf16x8* B31    = (bf16x8*)(ws + WS_OFF_B31);
    unsigned long long* part = (unsigned long long*)(ws + WS_OFF_PART);
    unsigned* cnt  = (unsigned*)(ws + WS_OFF_CNT);
    bf16x8* Pf     = (bf16x8*)(ws + WS_OFF_PF);

    k_prep<<<PREP_BLOCKS, 256, 0, stream>>>(P, CB, Bhh, B31, Pf, part, cnt);
    k_proj<<<PROJ_BLOCKS, 256, 0, stream>>>(x, Pf, AfragA, AfragB);
    k_scan<<<N_ROWGRP * CODEPARTS, 256, 0, stream>>>(
        AfragA, AfragB, Bhh, B31, part, cnt, out);                 // 1024 blocks
}

// Round 10
// 110.140 us; speedup vs baseline: 1.0290x; 1.0290x over previous
//
#include <hip/hip_runtime.h>
#include <stdint.h>

#define N_ROWS   16384
#define IN_DIM   512
#define CB_DIM   16
#define CB_VOCAB 8192

// ---- front geometry
#define PROJ_BLOCKS 1024                         // 1 row-tile each, 4-wave split-K
#define PREP_BLOCKS 128                          // 4 code-tiles each + part/cnt zero

// ---- scan geometry (R0/R8's proven 1024-block shape)
#define N_CT   (CB_VOCAB / 16)                   // 512 code-tiles
#define CODEPARTS 16
#define CT_PER_PART (N_CT / CODEPARTS)           // 32
#define N_ROWGRP 64                              // 256 rows per rowgrp

// ---- workspace layout (bytes), ~3.2 MB
#define WS_OFF_AFA  0                            // A-frag [A1|A2]: 1 MB
#define WS_OFF_AFB  (1u << 20)                   // A-frag [A1|A3]: 1 MB
#define WS_OFF_BHH  (2u << 20)                   // B-frag [B1;B2]: 512 KB
#define WS_OFF_B31  ((2u << 20) + (512u << 10))  // B-frag [B3;B1]: 512 KB
#define WS_OFF_PART (3u << 20)                   // u64[16384]: 128 KB
#define WS_OFF_CNT  ((3u << 20) + (128u << 10))  // u32[64]

typedef __attribute__((ext_vector_type(8))) short bf16x8;
typedef __attribute__((ext_vector_type(4))) float f32x4;

// monotone float -> uint32 key (order-preserving)
__device__ __forceinline__ unsigned fkey(float f) {
    unsigned u = __float_as_uint(f);
    return (u & 0x80000000u) ? ~u : (u | 0x80000000u);
}

// fp32 -> bf16 bits, round-to-nearest-even
__device__ __forceinline__ unsigned short f2bf(float f) {
    unsigned u = __float_as_uint(f);
    return (unsigned short)((u + 0x7FFFu + ((u >> 16) & 1u)) >> 16);
}
__device__ __forceinline__ float bf2f(unsigned short h) {
    return __uint_as_float(((unsigned)h) << 16);
}

// ---------------- K1: MFMA projection (blocks 0..1023) + prep (1024..1151) --
// BYTE-IDENTICAL to R8 (the 112.6-us best). Ledger: all front variants land
// at 27-31 us regardless of structure; leave it and keep attribution clean.
__global__ __launch_bounds__(256, 3)
void k_front(const float* __restrict__ x, const float* __restrict__ P,
             const float* __restrict__ CB,
             bf16x8* __restrict__ AfragA, bf16x8* __restrict__ AfragB,
             bf16x8* __restrict__ Bhh, bf16x8* __restrict__ B31,
             unsigned long long* __restrict__ part, unsigned* __restrict__ cnt) {
    __shared__ bf16x8 sPf[3][1024];              // P-frags, 3 levels: 48 KB
    __shared__ __align__(16) float foldb[1024];  // split-K fold / transpose: 4 KB

    const int tid  = threadIdx.x;
    const int wave = tid >> 6;
    const int lane = tid & 63;

    if (blockIdx.x >= PROJ_BLOCKS) {
        // ---- prep path: zero part/cnt, build CB B-frags ----
        const int pb = blockIdx.x - PROJ_BLOCKS;
        if (tid < 128) part[pb * 128 + tid] = 0ull;
        if (pb == 0 && tid < 64) cnt[tid] = 0u;

        const int ct   = pb * 4 + wave;
        const int n    = lane & 15;
        const int quad = lane >> 4;
        const int kh   = (quad & 1) * 8;
        const int lvl  = quad >> 1;
        const int code = ct * 16 + n;

        const float4* b4 = (const float4*)(CB + (size_t)code * CB_DIM + kh);
        float4 a = b4[0], b = b4[1];
        float v[8] = {a.x, a.y, a.z, a.w, b.x, b.y, b.z, b.w};

        bf16x8 shh, s31;
#pragma unroll
        for (int j = 0; j < 8; ++j) {
            float f = v[j];
            unsigned short b1 = f2bf(f);  float r1 = f - bf2f(b1);
            unsigned short b2 = f2bf(r1); float r2 = r1 - bf2f(b2);
            unsigned short b3 = f2bf(r2);
            shh[j] = (short)(lvl ? b2 : b1);
            s31[j] = (short)(lvl ? b1 : b3);
        }
        Bhh[(size_t)ct * 64 + lane] = shh;
        B31[(size_t)ct * 64 + lane] = s31;
        return;
    }

    // ---- Phase A: build P-frags in LDS (slot = chunk*64 + fraglane) ----
#pragma unroll
    for (int s4 = 0; s4 < 4; ++s4) {
        const int s  = tid + s4 * 256;
        const int c  = s >> 6;
        const int l  = s & 63;
        const int n  = l & 15;
        const int kq = l >> 4;
        const int k0 = c * 32 + kq * 8;

        bf16x8 p1, p2, p3;
#pragma unroll
        for (int j = 0; j < 8; ++j) {
            float f = P[(size_t)(k0 + j) * CB_DIM + n];
            unsigned short b1 = f2bf(f);  float r1 = f - bf2f(b1);
            unsigned short b2 = f2bf(r1); float r2 = r1 - bf2f(b2);
            unsigned short b3 = f2bf(r2);
            p1[j] = (short)b1; p2[j] = (short)b2; p3[j] = (short)b3;
        }
        sPf[0][s] = p1; sPf[1][s] = p2; sPf[2][s] = p3;
    }
    __syncthreads();

    // ---- Phase B: split-K proj; wave w covers chunks 4w..4w+3 ----
    const int rt = blockIdx.x;
    const int m  = lane & 15;
    const int kq = lane >> 4;
    const float4* xr = (const float4*)(x + (size_t)(rt * 16 + m) * IN_DIM);

    float4 xf[8];                                // all 8 x-loads issued upfront
#pragma unroll
    for (int i = 0; i < 4; ++i) {
        xf[2 * i]     = xr[(wave * 4 + i) * 8 + kq * 2];
        xf[2 * i + 1] = xr[(wave * 4 + i) * 8 + kq * 2 + 1];
    }

    f32x4 acc1 = {0.f, 0.f, 0.f, 0.f};
    f32x4 acc2 = {0.f, 0.f, 0.f, 0.f};

#pragma unroll
    for (int i = 0; i < 4; ++i) {
        const int c = wave * 4 + i;
        bf16x8 p1 = sPf[0][c * 64 + lane];
        bf16x8 p2 = sPf[1][c * 64 + lane];
        bf16x8 p3 = sPf[2][c * 64 + lane];

        float4 xa = xf[2 * i], xb = xf[2 * i + 1];
        float xs[8] = {xa.x, xa.y, xa.z, xa.w, xb.x, xb.y, xb.z, xb.w};
        bf16x8 a1, a2, a3;
#pragma unroll
        for (int j = 0; j < 8; ++j) {
            float f = xs[j];
            unsigned short b1 = f2bf(f);  float r1 = f - bf2f(b1);
            unsigned short b2 = f2bf(r1); float r2 = r1 - bf2f(b2);
            unsigned short b3 = f2bf(r2);
            a1[j] = (short)b1; a2[j] = (short)b2; a3[j] = (short)b3;
        }

        // terms i+j<=4: (1,1)(2,1)(2,2) chain1; (1,2)(1,3)(3,1) chain2
        acc1 = __builtin_amdgcn_mfma_f32_16x16x32_bf16(a1, p1, acc1, 0, 0, 0);
        acc2 = __builtin_amdgcn_mfma_f32_16x16x32_bf16(a1, p2, acc2, 0, 0, 0);
        acc1 = __builtin_amdgcn_mfma_f32_16x16x32_bf16(a2, p1, acc1, 0, 0, 0);
        acc2 = __builtin_amdgcn_mfma_f32_16x16x32_bf16(a1, p3, acc2, 0, 0, 0);
        acc1 = __builtin_amdgcn_mfma_f32_16x16x32_bf16(a2, p2, acc1, 0, 0, 0);
        acc2 = __builtin_amdgcn_mfma_f32_16x16x32_bf16(a3, p1, acc2, 0, 0, 0);
    }

    *(f32x4*)&foldb[(wave * 64 + lane) * 4] = acc1 + acc2;
    __syncthreads();

    // ---- Phase C (wave 0): fold partials, transpose, split, store ----
    if (wave == 0) {
        f32x4 s0 = *(const f32x4*)&foldb[(0 * 64 + lane) * 4];
        f32x4 s1 = *(const f32x4*)&foldb[(1 * 64 + lane) * 4];
        f32x4 s2 = *(const f32x4*)&foldb[(2 * 64 + lane) * 4];
        f32x4 s3 = *(const f32x4*)&foldb[(3 * 64 + lane) * 4];
        f32x4 sum = ((s0 + s1) + s2) + s3;

        // reads must retire before we overwrite foldb (rule 18 fence)
        asm volatile("s_waitcnt lgkmcnt(0)" ::: "memory");
        __builtin_amdgcn_sched_barrier(0);

        // C layout: lane holds xp[row=(kq*4+r)][col=m] -> transpose [16][20]
#pragma unroll
        for (int r = 0; r < 4; ++r)
            foldb[(kq * 4 + r) * 20 + m] = sum[r];

        asm volatile("s_waitcnt lgkmcnt(0)" ::: "memory");
        __builtin_amdgcn_sched_barrier(0);

        const int kh  = (kq & 1) * 8;
        const int lvl = kq >> 1;
        bf16x8 sa, sb;
#pragma unroll
        for (int j = 0; j < 8; ++j) {
            float f = foldb[m * 20 + kh + j];
            unsigned short b1 = f2bf(f);  float r1 = f - bf2f(b1);
            unsigned short b2 = f2bf(r1); float r2 = r1 - bf2f(b2);
            unsigned short b3 = f2bf(r2);
            sa[j] = (short)(lvl ? b2 : b1);
            sb[j] = (short)(lvl ? b3 : b1);
        }
        AfragA[(size_t)rt * 64 + lane] = sa;
        AfragB[(size_t)rt * 64 + lane] = sb;
    }
}

// ---------------- K2: MFMA sim + argmax + last-block finalize ---------------
// R10: R8's proven body (grid 1024, 4rt x 32ct, depth-1 named prefetch) with
// two stall-source removals:
// (1) LDS tail: the old tail was 16 (t,r) x 4 SERIALLY-DEPENDENT u64
//     __shfl_xor steps (2 ds_bpermute each, ~30-60 cyc latency) ~ 3800 cyc
//     of mostly-stall per wave (~1/3 of wave time). Now: all lanes write
//     their packed u64 candidate to a transposed padded LDS array
//     Lcand[16 cand][257 rows], one barrier, then thread i max-reduces row
//     i's 16 candidates serially (15 u64 cmps, no cross-lane ops) and does
//     the same single atomicMax. Value-identical (same packed max, same
//     tie-break).
// (2) s_setprio(1) around the MFMA cluster (T5): scan waves free-run with no
//     body barriers -- the phase-diverse regime where T5 measured +4-7%
//     (m191), not the lockstep-null regime (m190).
// LDS 33 KB -> still 4 blocks/CU at (256,4).
__global__ __launch_bounds__(256, 4)
void k_scan(const bf16x8* __restrict__ AfragA, const bf16x8* __restrict__ AfragB,
            const bf16x8* __restrict__ Bhh, const bf16x8* __restrict__ B31,
            unsigned long long* __restrict__ part, unsigned* __restrict__ cnt,
            int* __restrict__ out) {
    __shared__ unsigned long long Lcand[16][257];  // [cand n][row_loc], padded
    __shared__ int s_done;
    const int codepart = blockIdx.x & (CODEPARTS - 1);
    const int rowgrp   = blockIdx.x >> 4;
    const int wave     = threadIdx.x >> 6;
    const int lane     = threadIdx.x & 63;
    const int n        = lane & 15;
    const int quad     = lane >> 4;
    const int rt_base  = rowgrp * 16 + wave * 4;

    bf16x8 Aa[4], Ab[4];
#pragma unroll
    for (int t = 0; t < 4; ++t) {
        Aa[t] = AfragA[(size_t)(rt_base + t) * 64 + lane];
        Ab[t] = AfragB[(size_t)(rt_base + t) * 64 + lane];
    }

    float bestv[4][4];
    int   bestc[4][4];
#pragma unroll
    for (int t = 0; t < 4; ++t)
#pragma unroll
        for (int r = 0; r < 4; ++r) { bestv[t][r] = -INFINITY; bestc[t][r] = 0; }

    const int ct0 = codepart * CT_PER_PART;
    size_t ib = (size_t)ct0 * 64;
    bf16x8 nb1  = Bhh[ib + lane];
    bf16x8 nb1s = Bhh[ib + (lane ^ 32)];
    bf16x8 nb3  = B31[ib + lane];

    for (int c = 0; c < CT_PER_PART; ++c) {
        bf16x8 b1 = nb1, b1s = nb1s, b3 = nb3;
        if (c + 1 < CT_PER_PART) {
            size_t ibn = (size_t)(ct0 + c + 1) * 64;
            nb1  = Bhh[ibn + lane];
            nb1s = Bhh[ibn + (lane ^ 32)];
            nb3  = B31[ibn + lane];
        }
        __builtin_amdgcn_s_setprio(1);
#pragma unroll
        for (int t = 0; t < 4; ++t) {
            f32x4 s = __builtin_amdgcn_mfma_f32_16x16x32_bf16(
                          Aa[t], b1, (f32x4){0.f, 0.f, 0.f, 0.f}, 0, 0, 0);
            s = __builtin_amdgcn_mfma_f32_16x16x32_bf16(Aa[t], b1s, s, 0, 0, 0);
            s = __builtin_amdgcn_mfma_f32_16x16x32_bf16(Ab[t], b3,  s, 0, 0, 0);
#pragma unroll
            for (int r = 0; r < 4; ++r) {
                if (s[r] > bestv[t][r]) { bestv[t][r] = s[r]; bestc[t][r] = c; }
            }
        }
        __builtin_amdgcn_s_setprio(0);
    }

    // ---- LDS tail: every lane deposits its candidate; no cross-lane ops ----
#pragma unroll
    for (int t = 0; t < 4; ++t) {
#pragma unroll
        for (int r = 0; r < 4; ++r) {
            unsigned code = (unsigned)(codepart * 512 + bestc[t][r] * 16 + n);
            unsigned long long packed =
                ((unsigned long long)fkey(bestv[t][r]) << 32) |
                (unsigned long long)(0xFFFFFFFFu - code);
            const int row_loc = (wave * 4 + t) * 16 + quad * 4 + r;
            Lcand[n][row_loc] = packed;
        }
    }
    __syncthreads();

    // thread i owns block-row i: serial max over its 16 candidates, 1 atomic
    {
        const int i = threadIdx.x;                // 0..255 == row_loc
        unsigned long long best = Lcand[0][i];
#pragma unroll
        for (int j = 1; j < 16; ++j) {
            unsigned long long v = Lcand[j][i];
            best = (v > best) ? v : best;
        }
        atomicMax(&part[rowgrp * 256 + i], best);
    }

    // __syncthreads drains vmcnt -> all this block's atomics are complete
    __syncthreads();
    if (threadIdx.x == 0)
        s_done = (atomicAdd(&cnt[rowgrp], 1u) == (unsigned)(CODEPARTS - 1));
    __syncthreads();

    if (s_done) {
        int row = rowgrp * 256 + threadIdx.x;
        unsigned long long v = atomicAdd(&part[row], 0ull);   // coherent read
        out[row] = (int)(0xFFFFFFFFu - (unsigned)(v & 0xFFFFFFFFull));
    }
}

extern "C" void kernel_launch(void* const* d_in, const int* in_sizes, int n_in,
                              void* d_out, int out_size, void* d_ws, size_t ws_size,
                              hipStream_t stream) {
    const float* x  = (const float*)d_in[0];   // [16384, 512]
    const float* P  = (const float*)d_in[1];   // [512, 16]
    const float* CB = (const float*)d_in[2];   // [8192, 16]
    int* out = (int*)d_out;                    // [16384] int32

    char* ws = (char*)d_ws;
    bf16x8* AfragA = (bf16x8*)(ws + WS_OFF_AFA);
    bf16x8* AfragB = (bf16x8*)(ws + WS_OFF_AFB);
    bf16x8* Bhh    = (bf16x8*)(ws + WS_OFF_BHH);
    bf16x8* B31    = (bf16x8*)(ws + WS_OFF_B31);
    unsigned long long* part = (unsigned long long*)(ws + WS_OFF_PART);
    unsigned* cnt  = (unsigned*)(ws + WS_OFF_CNT);

    k_front<<<PROJ_BLOCKS + PREP_BLOCKS, 256, 0, stream>>>(
        x, P, CB, AfragA, AfragB, Bhh, B31, part, cnt);            // 1152 blocks
    k_scan<<<N_ROWGRP * CODEPARTS, 256, 0, stream>>>(
        AfragA, AfragB, Bhh, B31, part, cnt, out);                 // 1024 blocks
}

// Round 11
// 107.930 us; speedup vs baseline: 1.0500x; 1.0205x over previous
//
#include <hip/hip_runtime.h>
#include <stdint.h>

#define N_ROWS   16384
#define IN_DIM   512
#define CB_DIM   16
#define CB_VOCAB 8192

// ---- front geometry
#define PROJ_BLOCKS 1024                         // 1 row-tile each, 4-wave split-K
#define PREP_BLOCKS 128                          // 4 code-tiles each + part/cnt zero

// ---- scan geometry: R11 = R10 text with CODEPARTS 16 -> 8 (64 iters/block).
// Trend data: scan @16 iters = 50 us (R4), @32 iters = 36-39 (R0/R8/R10) --
// per-block fixed cost (prologue + LDS tail + atomics + finalize) amortizes
// with iters. 8 codeparts also halves B-frag L2 re-reads and atomic count.
#define N_CT   (CB_VOCAB / 16)                   // 512 code-tiles
#define CODEPARTS 8
#define CT_PER_PART (N_CT / CODEPARTS)           // 64
#define N_ROWGRP 64                              // 256 rows per rowgrp

// ---- workspace layout (bytes), ~3.2 MB
#define WS_OFF_AFA  0                            // A-frag [A1|A2]: 1 MB
#define WS_OFF_AFB  (1u << 20)                   // A-frag [A1|A3]: 1 MB
#define WS_OFF_BHH  (2u << 20)                   // B-frag [B1;B2]: 512 KB
#define WS_OFF_B31  ((2u << 20) + (512u << 10))  // B-frag [B3;B1]: 512 KB
#define WS_OFF_PART (3u << 20)                   // u64[16384]: 128 KB
#define WS_OFF_CNT  ((3u << 20) + (128u << 10))  // u32[64]

typedef __attribute__((ext_vector_type(8))) short bf16x8;
typedef __attribute__((ext_vector_type(4))) float f32x4;

// monotone float -> uint32 key (order-preserving)
__device__ __forceinline__ unsigned fkey(float f) {
    unsigned u = __float_as_uint(f);
    return (u & 0x80000000u) ? ~u : (u | 0x80000000u);
}

// fp32 -> bf16 bits, round-to-nearest-even
__device__ __forceinline__ unsigned short f2bf(float f) {
    unsigned u = __float_as_uint(f);
    return (unsigned short)((u + 0x7FFFu + ((u >> 16) & 1u)) >> 16);
}
__device__ __forceinline__ float bf2f(unsigned short h) {
    return __uint_as_float(((unsigned)h) << 16);
}

// ---------------- K1: MFMA projection (blocks 0..1023) + prep (1024..1151) --
// BYTE-IDENTICAL to R10 (the 110.1-us best). Ledger: all front variants land
// at 27-31 us regardless of structure; leave it and keep attribution clean.
__global__ __launch_bounds__(256, 3)
void k_front(const float* __restrict__ x, const float* __restrict__ P,
             const float* __restrict__ CB,
             bf16x8* __restrict__ AfragA, bf16x8* __restrict__ AfragB,
             bf16x8* __restrict__ Bhh, bf16x8* __restrict__ B31,
             unsigned long long* __restrict__ part, unsigned* __restrict__ cnt) {
    __shared__ bf16x8 sPf[3][1024];              // P-frags, 3 levels: 48 KB
    __shared__ __align__(16) float foldb[1024];  // split-K fold / transpose: 4 KB

    const int tid  = threadIdx.x;
    const int wave = tid >> 6;
    const int lane = tid & 63;

    if (blockIdx.x >= PROJ_BLOCKS) {
        // ---- prep path: zero part/cnt, build CB B-frags ----
        const int pb = blockIdx.x - PROJ_BLOCKS;
        if (tid < 128) part[pb * 128 + tid] = 0ull;
        if (pb == 0 && tid < 64) cnt[tid] = 0u;

        const int ct   = pb * 4 + wave;
        const int n    = lane & 15;
        const int quad = lane >> 4;
        const int kh   = (quad & 1) * 8;
        const int lvl  = quad >> 1;
        const int code = ct * 16 + n;

        const float4* b4 = (const float4*)(CB + (size_t)code * CB_DIM + kh);
        float4 a = b4[0], b = b4[1];
        float v[8] = {a.x, a.y, a.z, a.w, b.x, b.y, b.z, b.w};

        bf16x8 shh, s31;
#pragma unroll
        for (int j = 0; j < 8; ++j) {
            float f = v[j];
            unsigned short b1 = f2bf(f);  float r1 = f - bf2f(b1);
            unsigned short b2 = f2bf(r1); float r2 = r1 - bf2f(b2);
            unsigned short b3 = f2bf(r2);
            shh[j] = (short)(lvl ? b2 : b1);
            s31[j] = (short)(lvl ? b1 : b3);
        }
        Bhh[(size_t)ct * 64 + lane] = shh;
        B31[(size_t)ct * 64 + lane] = s31;
        return;
    }

    // ---- Phase A: build P-frags in LDS (slot = chunk*64 + fraglane) ----
#pragma unroll
    for (int s4 = 0; s4 < 4; ++s4) {
        const int s  = tid + s4 * 256;
        const int c  = s >> 6;
        const int l  = s & 63;
        const int n  = l & 15;
        const int kq = l >> 4;
        const int k0 = c * 32 + kq * 8;

        bf16x8 p1, p2, p3;
#pragma unroll
        for (int j = 0; j < 8; ++j) {
            float f = P[(size_t)(k0 + j) * CB_DIM + n];
            unsigned short b1 = f2bf(f);  float r1 = f - bf2f(b1);
            unsigned short b2 = f2bf(r1); float r2 = r1 - bf2f(b2);
            unsigned short b3 = f2bf(r2);
            p1[j] = (short)b1; p2[j] = (short)b2; p3[j] = (short)b3;
        }
        sPf[0][s] = p1; sPf[1][s] = p2; sPf[2][s] = p3;
    }
    __syncthreads();

    // ---- Phase B: split-K proj; wave w covers chunks 4w..4w+3 ----
    const int rt = blockIdx.x;
    const int m  = lane & 15;
    const int kq = lane >> 4;
    const float4* xr = (const float4*)(x + (size_t)(rt * 16 + m) * IN_DIM);

    float4 xf[8];                                // all 8 x-loads issued upfront
#pragma unroll
    for (int i = 0; i < 4; ++i) {
        xf[2 * i]     = xr[(wave * 4 + i) * 8 + kq * 2];
        xf[2 * i + 1] = xr[(wave * 4 + i) * 8 + kq * 2 + 1];
    }

    f32x4 acc1 = {0.f, 0.f, 0.f, 0.f};
    f32x4 acc2 = {0.f, 0.f, 0.f, 0.f};

#pragma unroll
    for (int i = 0; i < 4; ++i) {
        const int c = wave * 4 + i;
        bf16x8 p1 = sPf[0][c * 64 + lane];
        bf16x8 p2 = sPf[1][c * 64 + lane];
        bf16x8 p3 = sPf[2][c * 64 + lane];

        float4 xa = xf[2 * i], xb = xf[2 * i + 1];
        float xs[8] = {xa.x, xa.y, xa.z, xa.w, xb.x, xb.y, xb.z, xb.w};
        bf16x8 a1, a2, a3;
#pragma unroll
        for (int j = 0; j < 8; ++j) {
            float f = xs[j];
            unsigned short b1 = f2bf(f);  float r1 = f - bf2f(b1);
            unsigned short b2 = f2bf(r1); float r2 = r1 - bf2f(b2);
            unsigned short b3 = f2bf(r2);
            a1[j] = (short)b1; a2[j] = (short)b2; a3[j] = (short)b3;
        }

        // terms i+j<=4: (1,1)(2,1)(2,2) chain1; (1,2)(1,3)(3,1) chain2
        acc1 = __builtin_amdgcn_mfma_f32_16x16x32_bf16(a1, p1, acc1, 0, 0, 0);
        acc2 = __builtin_amdgcn_mfma_f32_16x16x32_bf16(a1, p2, acc2, 0, 0, 0);
        acc1 = __builtin_amdgcn_mfma_f32_16x16x32_bf16(a2, p1, acc1, 0, 0, 0);
        acc2 = __builtin_amdgcn_mfma_f32_16x16x32_bf16(a1, p3, acc2, 0, 0, 0);
        acc1 = __builtin_amdgcn_mfma_f32_16x16x32_bf16(a2, p2, acc1, 0, 0, 0);
        acc2 = __builtin_amdgcn_mfma_f32_16x16x32_bf16(a3, p1, acc2, 0, 0, 0);
    }

    *(f32x4*)&foldb[(wave * 64 + lane) * 4] = acc1 + acc2;
    __syncthreads();

    // ---- Phase C (wave 0): fold partials, transpose, split, store ----
    if (wave == 0) {
        f32x4 s0 = *(const f32x4*)&foldb[(0 * 64 + lane) * 4];
        f32x4 s1 = *(const f32x4*)&foldb[(1 * 64 + lane) * 4];
        f32x4 s2 = *(const f32x4*)&foldb[(2 * 64 + lane) * 4];
        f32x4 s3 = *(const f32x4*)&foldb[(3 * 64 + lane) * 4];
        f32x4 sum = ((s0 + s1) + s2) + s3;

        // reads must retire before we overwrite foldb (rule 18 fence)
        asm volatile("s_waitcnt lgkmcnt(0)" ::: "memory");
        __builtin_amdgcn_sched_barrier(0);

        // C layout: lane holds xp[row=(kq*4+r)][col=m] -> transpose [16][20]
#pragma unroll
        for (int r = 0; r < 4; ++r)
            foldb[(kq * 4 + r) * 20 + m] = sum[r];

        asm volatile("s_waitcnt lgkmcnt(0)" ::: "memory");
        __builtin_amdgcn_sched_barrier(0);

        const int kh  = (kq & 1) * 8;
        const int lvl = kq >> 1;
        bf16x8 sa, sb;
#pragma unroll
        for (int j = 0; j < 8; ++j) {
            float f = foldb[m * 20 + kh + j];
            unsigned short b1 = f2bf(f);  float r1 = f - bf2f(b1);
            unsigned short b2 = f2bf(r1); float r2 = r1 - bf2f(b2);
            unsigned short b3 = f2bf(r2);
            sa[j] = (short)(lvl ? b2 : b1);
            sb[j] = (short)(lvl ? b3 : b1);
        }
        AfragA[(size_t)rt * 64 + lane] = sa;
        AfragB[(size_t)rt * 64 + lane] = sb;
    }
}

// ---------------- K2: MFMA sim + argmax + last-block finalize ---------------
// R11 = R10's proven body (LDS tail + setprio), CODEPARTS 16 -> 8: grid 512
// = 64 rowgrps x 8 codeparts, 64 c-iters/block. Fixed per-block cost
// (prologue, tail reduce, atomics, finalize) amortized 2x; B-frag L2
// re-reads halve; atomicMax count halves. Loop body, register budget, LDS
// byte-identical to R10.
__global__ __launch_bounds__(256, 4)
void k_scan(const bf16x8* __restrict__ AfragA, const bf16x8* __restrict__ AfragB,
            const bf16x8* __restrict__ Bhh, const bf16x8* __restrict__ B31,
            unsigned long long* __restrict__ part, unsigned* __restrict__ cnt,
            int* __restrict__ out) {
    __shared__ unsigned long long Lcand[16][257];  // [cand n][row_loc], padded
    __shared__ int s_done;
    const int codepart = blockIdx.x & (CODEPARTS - 1);
    const int rowgrp   = blockIdx.x >> 3;
    const int wave     = threadIdx.x >> 6;
    const int lane     = threadIdx.x & 63;
    const int n        = lane & 15;
    const int quad     = lane >> 4;
    const int rt_base  = rowgrp * 16 + wave * 4;

    bf16x8 Aa[4], Ab[4];
#pragma unroll
    for (int t = 0; t < 4; ++t) {
        Aa[t] = AfragA[(size_t)(rt_base + t) * 64 + lane];
        Ab[t] = AfragB[(size_t)(rt_base + t) * 64 + lane];
    }

    float bestv[4][4];
    int   bestc[4][4];
#pragma unroll
    for (int t = 0; t < 4; ++t)
#pragma unroll
        for (int r = 0; r < 4; ++r) { bestv[t][r] = -INFINITY; bestc[t][r] = 0; }

    const int ct0 = codepart * CT_PER_PART;
    size_t ib = (size_t)ct0 * 64;
    bf16x8 nb1  = Bhh[ib + lane];
    bf16x8 nb1s = Bhh[ib + (lane ^ 32)];
    bf16x8 nb3  = B31[ib + lane];

    for (int c = 0; c < CT_PER_PART; ++c) {
        bf16x8 b1 = nb1, b1s = nb1s, b3 = nb3;
        if (c + 1 < CT_PER_PART) {
            size_t ibn = (size_t)(ct0 + c + 1) * 64;
            nb1  = Bhh[ibn + lane];
            nb1s = Bhh[ibn + (lane ^ 32)];
            nb3  = B31[ibn + lane];
        }
        __builtin_amdgcn_s_setprio(1);
#pragma unroll
        for (int t = 0; t < 4; ++t) {
            f32x4 s = __builtin_amdgcn_mfma_f32_16x16x32_bf16(
                          Aa[t], b1, (f32x4){0.f, 0.f, 0.f, 0.f}, 0, 0, 0);
            s = __builtin_amdgcn_mfma_f32_16x16x32_bf16(Aa[t], b1s, s, 0, 0, 0);
            s = __builtin_amdgcn_mfma_f32_16x16x32_bf16(Ab[t], b3,  s, 0, 0, 0);
#pragma unroll
            for (int r = 0; r < 4; ++r) {
                if (s[r] > bestv[t][r]) { bestv[t][r] = s[r]; bestc[t][r] = c; }
            }
        }
        __builtin_amdgcn_s_setprio(0);
    }

    // ---- LDS tail: every lane deposits its candidate; no cross-lane ops ----
#pragma unroll
    for (int t = 0; t < 4; ++t) {
#pragma unroll
        for (int r = 0; r < 4; ++r) {
            unsigned code = (unsigned)(codepart * (CT_PER_PART * 16) +
                                       bestc[t][r] * 16 + n);
            unsigned long long packed =
                ((unsigned long long)fkey(bestv[t][r]) << 32) |
                (unsigned long long)(0xFFFFFFFFu - code);
            const int row_loc = (wave * 4 + t) * 16 + quad * 4 + r;
            Lcand[n][row_loc] = packed;
        }
    }
    __syncthreads();

    // thread i owns block-row i: serial max over its 16 candidates, 1 atomic
    {
        const int i = threadIdx.x;                // 0..255 == row_loc
        unsigned long long best = Lcand[0][i];
#pragma unroll
        for (int j = 1; j < 16; ++j) {
            unsigned long long v = Lcand[j][i];
            best = (v > best) ? v : best;
        }
        atomicMax(&part[rowgrp * 256 + i], best);
    }

    // __syncthreads drains vmcnt -> all this block's atomics are complete
    __syncthreads();
    if (threadIdx.x == 0)
        s_done = (atomicAdd(&cnt[rowgrp], 1u) == (unsigned)(CODEPARTS - 1));
    __syncthreads();

    if (s_done) {
        int row = rowgrp * 256 + threadIdx.x;
        unsigned long long v = atomicAdd(&part[row], 0ull);   // coherent read
        out[row] = (int)(0xFFFFFFFFu - (unsigned)(v & 0xFFFFFFFFull));
    }
}

extern "C" void kernel_launch(void* const* d_in, const int* in_sizes, int n_in,
                              void* d_out, int out_size, void* d_ws, size_t ws_size,
                              hipStream_t stream) {
    const float* x  = (const float*)d_in[0];   // [16384, 512]
    const float* P  = (const float*)d_in[1];   // [512, 16]
    const float* CB = (const float*)d_in[2];   // [8192, 16]
    int* out = (int*)d_out;                    // [16384] int32

    char* ws = (char*)d_ws;
    bf16x8* AfragA = (bf16x8*)(ws + WS_OFF_AFA);
    bf16x8* AfragB = (bf16x8*)(ws + WS_OFF_AFB);
    bf16x8* Bhh    = (bf16x8*)(ws + WS_OFF_BHH);
    bf16x8* B31    = (bf16x8*)(ws + WS_OFF_B31);
    unsigned long long* part = (unsigned long long*)(ws + WS_OFF_PART);
    unsigned* cnt  = (unsigned*)(ws + WS_OFF_CNT);

    k_front<<<PROJ_BLOCKS + PREP_BLOCKS, 256, 0, stream>>>(
        x, P, CB, AfragA, AfragB, Bhh, B31, part, cnt);            // 1152 blocks
    k_scan<<<N_ROWGRP * CODEPARTS, 256, 0, stream>>>(
        AfragA, AfragB, Bhh, B31, part, cnt, out);                 // 512 blocks
}

// Round 12
// 106.430 us; speedup vs baseline: 1.0648x; 1.0141x over previous
//
#include <hip/hip_runtime.h>
#include <stdint.h>

#define N_ROWS   16384
#define IN_DIM   512
#define CB_DIM   16
#define CB_VOCAB 8192

// ---- front geometry
#define PROJ_BLOCKS 1024                         // 1 row-tile each, 4-wave split-K
#define PREP_BLOCKS 128                          // 4 code-tiles each + part/cnt zero

// ---- scan geometry (R11's measured ~34us shape)
#define N_CT   (CB_VOCAB / 16)                   // 512 code-tiles
#define CODEPARTS 8
#define CT_PER_PART (N_CT / CODEPARTS)           // 64
#define N_ROWGRP 64                              // 256 rows per rowgrp

// ---- workspace layout (bytes), ~3.2 MB
#define WS_OFF_AFA  0                            // A-frag [A1|A2]: 1 MB
#define WS_OFF_AFB  (1u << 20)                   // A-frag [A1|A3]: 1 MB
#define WS_OFF_BHH  (2u << 20)                   // B-frag [B1;B2]: 512 KB
#define WS_OFF_B31  ((2u << 20) + (512u << 10))  // B-frag [B3;B1]: 512 KB
#define WS_OFF_PART (3u << 20)                   // u64[16384]: 128 KB
#define WS_OFF_CNT  ((3u << 20) + (128u << 10))  // u32[64]

typedef __attribute__((ext_vector_type(8))) short bf16x8;
typedef __attribute__((ext_vector_type(4))) float f32x4;

// monotone float -> uint32 key (order-preserving)
__device__ __forceinline__ unsigned fkey(float f) {
    unsigned u = __float_as_uint(f);
    return (u & 0x80000000u) ? ~u : (u | 0x80000000u);
}

// fp32 -> bf16 bits, round-to-nearest-even
__device__ __forceinline__ unsigned short f2bf(float f) {
    unsigned u = __float_as_uint(f);
    return (unsigned short)((u + 0x7FFFu + ((u >> 16) & 1u)) >> 16);
}
__device__ __forceinline__ float bf2f(unsigned short h) {
    return __uint_as_float(((unsigned)h) << 16);
}

// ---------------- K1: MFMA projection (blocks 0..1023) + prep (1024..1151) --
// R12 front: per-block de-fat. R11's Phase A (cooperative 48 KB LDS P-frag
// table: 32 scalar P loads + RNE splits + 12 ds_writes + barrier + 12
// ds_reads per thread) is replaced by REGISTER P-frags: wave w only consumes
// chunks 4w..4w+3 at its own lane, so each thread computes exactly its 12
// B-frags from the same 32 L2-hot scalar P loads -- no LDS table, no
// barrier. LDS 52 KB -> 4 KB (occupancy now VGPR-bound, ~4 blocks/CU).
// Hot-loop splits (P and x) switch RNE -> TRUNCATE: exact decomposition
// (8+8+8 mantissa bits; every residual representable), 7 ops/value vs 19
// (saves ~768 VALU cyc/wave; R9 precedent: truncate-x passed absmax 0).
// Phase C epilogue (once/block) keeps RNE for A-frag emission -- scan
// interface unchanged.
__global__ __launch_bounds__(256, 3)
void k_front(const float* __restrict__ x, const float* __restrict__ P,
             const float* __restrict__ CB,
             bf16x8* __restrict__ AfragA, bf16x8* __restrict__ AfragB,
             bf16x8* __restrict__ Bhh, bf16x8* __restrict__ B31,
             unsigned long long* __restrict__ part, unsigned* __restrict__ cnt) {
    __shared__ __align__(16) float foldb[1024];  // split-K fold / transpose: 4 KB

    const int tid  = threadIdx.x;
    const int wave = tid >> 6;
    const int lane = tid & 63;

    if (blockIdx.x >= PROJ_BLOCKS) {
        // ---- prep path: zero part/cnt, build CB B-frags (unchanged) ----
        const int pb = blockIdx.x - PROJ_BLOCKS;
        if (tid < 128) part[pb * 128 + tid] = 0ull;
        if (pb == 0 && tid < 64) cnt[tid] = 0u;

        const int ct   = pb * 4 + wave;
        const int n    = lane & 15;
        const int quad = lane >> 4;
        const int kh   = (quad & 1) * 8;
        const int lvl  = quad >> 1;
        const int code = ct * 16 + n;

        const float4* b4 = (const float4*)(CB + (size_t)code * CB_DIM + kh);
        float4 a = b4[0], b = b4[1];
        float v[8] = {a.x, a.y, a.z, a.w, b.x, b.y, b.z, b.w};

        bf16x8 shh, s31;
#pragma unroll
        for (int j = 0; j < 8; ++j) {
            float f = v[j];
            unsigned short b1 = f2bf(f);  float r1 = f - bf2f(b1);
            unsigned short b2 = f2bf(r1); float r2 = r1 - bf2f(b2);
            unsigned short b3 = f2bf(r2);
            shh[j] = (short)(lvl ? b2 : b1);
            s31[j] = (short)(lvl ? b1 : b3);
        }
        Bhh[(size_t)ct * 64 + lane] = shh;
        B31[(size_t)ct * 64 + lane] = s31;
        return;
    }

    // ---- proj: split-K, register P-frags; wave w covers chunks 4w..4w+3 ----
    const int rt = blockIdx.x;
    const int m  = lane & 15;
    const int kq = lane >> 4;
    const float4* xr = (const float4*)(x + (size_t)(rt * 16 + m) * IN_DIM);

    float4 xf[8];                                // all 8 x-loads issued upfront
#pragma unroll
    for (int i = 0; i < 4; ++i) {
        xf[2 * i]     = xr[(wave * 4 + i) * 8 + kq * 2];
        xf[2 * i + 1] = xr[(wave * 4 + i) * 8 + kq * 2 + 1];
    }

    // raw P loads for this lane's 4 chunks (upfront, L2-hot; static idx)
    float praw[4][8];
#pragma unroll
    for (int i = 0; i < 4; ++i) {
        const float* pg =
            P + (size_t)((wave * 4 + i) * 32 + kq * 8) * CB_DIM + m;
#pragma unroll
        for (int j = 0; j < 8; ++j) praw[i][j] = pg[j * CB_DIM];
    }

    f32x4 acc1 = {0.f, 0.f, 0.f, 0.f};
    f32x4 acc2 = {0.f, 0.f, 0.f, 0.f};

#pragma unroll
    for (int i = 0; i < 4; ++i) {
        bf16x8 p1, p2, p3;
#pragma unroll
        for (int j = 0; j < 8; ++j) {
            // truncate split: exact f = p1 + p2 + p3
            float f = praw[i][j];
            unsigned u  = __float_as_uint(f);
            unsigned h1 = u & 0xFFFF0000u;
            float r1 = f - __uint_as_float(h1);
            unsigned u2 = __float_as_uint(r1);
            float r2 = r1 - __uint_as_float(u2 & 0xFFFF0000u);
            p1[j] = (short)(h1 >> 16);
            p2[j] = (short)(u2 >> 16);
            p3[j] = (short)(__float_as_uint(r2) >> 16);
        }

        float4 xa = xf[2 * i], xb = xf[2 * i + 1];
        float xs[8] = {xa.x, xa.y, xa.z, xa.w, xb.x, xb.y, xb.z, xb.w};
        bf16x8 a1, a2, a3;
#pragma unroll
        for (int j = 0; j < 8; ++j) {
            // truncate split: exact f = a1 + a2 + a3
            float f = xs[j];
            unsigned u  = __float_as_uint(f);
            unsigned h1 = u & 0xFFFF0000u;
            float r1 = f - __uint_as_float(h1);
            unsigned u2 = __float_as_uint(r1);
            float r2 = r1 - __uint_as_float(u2 & 0xFFFF0000u);
            a1[j] = (short)(h1 >> 16);
            a2[j] = (short)(u2 >> 16);
            a3[j] = (short)(__float_as_uint(r2) >> 16);
        }

        // terms i+j<=4: (1,1)(2,1)(2,2) chain1; (1,2)(1,3)(3,1) chain2
        acc1 = __builtin_amdgcn_mfma_f32_16x16x32_bf16(a1, p1, acc1, 0, 0, 0);
        acc2 = __builtin_amdgcn_mfma_f32_16x16x32_bf16(a1, p2, acc2, 0, 0, 0);
        acc1 = __builtin_amdgcn_mfma_f32_16x16x32_bf16(a2, p1, acc1, 0, 0, 0);
        acc2 = __builtin_amdgcn_mfma_f32_16x16x32_bf16(a1, p3, acc2, 0, 0, 0);
        acc1 = __builtin_amdgcn_mfma_f32_16x16x32_bf16(a2, p2, acc1, 0, 0, 0);
        acc2 = __builtin_amdgcn_mfma_f32_16x16x32_bf16(a3, p1, acc2, 0, 0, 0);
    }

    *(f32x4*)&foldb[(wave * 64 + lane) * 4] = acc1 + acc2;
    __syncthreads();

    // ---- Phase C (wave 0): fold partials, transpose, split, store ----
    if (wave == 0) {
        f32x4 s0 = *(const f32x4*)&foldb[(0 * 64 + lane) * 4];
        f32x4 s1 = *(const f32x4*)&foldb[(1 * 64 + lane) * 4];
        f32x4 s2 = *(const f32x4*)&foldb[(2 * 64 + lane) * 4];
        f32x4 s3 = *(const f32x4*)&foldb[(3 * 64 + lane) * 4];
        f32x4 sum = ((s0 + s1) + s2) + s3;

        // reads must retire before we overwrite foldb (rule 18 fence)
        asm volatile("s_waitcnt lgkmcnt(0)" ::: "memory");
        __builtin_amdgcn_sched_barrier(0);

        // C layout: lane holds xp[row=(kq*4+r)][col=m] -> transpose [16][20]
#pragma unroll
        for (int r = 0; r < 4; ++r)
            foldb[(kq * 4 + r) * 20 + m] = sum[r];

        asm volatile("s_waitcnt lgkmcnt(0)" ::: "memory");
        __builtin_amdgcn_sched_barrier(0);

        const int kh  = (kq & 1) * 8;
        const int lvl = kq >> 1;
        bf16x8 sa, sb;
#pragma unroll
        for (int j = 0; j < 8; ++j) {
            float f = foldb[m * 20 + kh + j];
            unsigned short b1 = f2bf(f);  float r1 = f - bf2f(b1);
            unsigned short b2 = f2bf(r1); float r2 = r1 - bf2f(b2);
            unsigned short b3 = f2bf(r2);
            sa[j] = (short)(lvl ? b2 : b1);
            sb[j] = (short)(lvl ? b3 : b1);
        }
        AfragA[(size_t)rt * 64 + lane] = sa;
        AfragB[(size_t)rt * 64 + lane] = sb;
    }
}

// ---------------- K2: MFMA sim + argmax + last-block finalize ---------------
// BYTE-IDENTICAL to R11 (measured ~34 us): grid 512 = 64 rowgrps x 8
// codeparts, 64 c-iters/block, depth-1 named prefetch, LDS tail, setprio.
__global__ __launch_bounds__(256, 4)
void k_scan(const bf16x8* __restrict__ AfragA, const bf16x8* __restrict__ AfragB,
            const bf16x8* __restrict__ Bhh, const bf16x8* __restrict__ B31,
            unsigned long long* __restrict__ part, unsigned* __restrict__ cnt,
            int* __restrict__ out) {
    __shared__ unsigned long long Lcand[16][257];  // [cand n][row_loc], padded
    __shared__ int s_done;
    const int codepart = blockIdx.x & (CODEPARTS - 1);
    const int rowgrp   = blockIdx.x >> 3;
    const int wave     = threadIdx.x >> 6;
    const int lane     = threadIdx.x & 63;
    const int n        = lane & 15;
    const int quad     = lane >> 4;
    const int rt_base  = rowgrp * 16 + wave * 4;

    bf16x8 Aa[4], Ab[4];
#pragma unroll
    for (int t = 0; t < 4; ++t) {
        Aa[t] = AfragA[(size_t)(rt_base + t) * 64 + lane];
        Ab[t] = AfragB[(size_t)(rt_base + t) * 64 + lane];
    }

    float bestv[4][4];
    int   bestc[4][4];
#pragma unroll
    for (int t = 0; t < 4; ++t)
#pragma unroll
        for (int r = 0; r < 4; ++r) { bestv[t][r] = -INFINITY; bestc[t][r] = 0; }

    const int ct0 = codepart * CT_PER_PART;
    size_t ib = (size_t)ct0 * 64;
    bf16x8 nb1  = Bhh[ib + lane];
    bf16x8 nb1s = Bhh[ib + (lane ^ 32)];
    bf16x8 nb3  = B31[ib + lane];

    for (int c = 0; c < CT_PER_PART; ++c) {
        bf16x8 b1 = nb1, b1s = nb1s, b3 = nb3;
        if (c + 1 < CT_PER_PART) {
            size_t ibn = (size_t)(ct0 + c + 1) * 64;
            nb1  = Bhh[ibn + lane];
            nb1s = Bhh[ibn + (lane ^ 32)];
            nb3  = B31[ibn + lane];
        }
        __builtin_amdgcn_s_setprio(1);
#pragma unroll
        for (int t = 0; t < 4; ++t) {
            f32x4 s = __builtin_amdgcn_mfma_f32_16x16x32_bf16(
                          Aa[t], b1, (f32x4){0.f, 0.f, 0.f, 0.f}, 0, 0, 0);
            s = __builtin_amdgcn_mfma_f32_16x16x32_bf16(Aa[t], b1s, s, 0, 0, 0);
            s = __builtin_amdgcn_mfma_f32_16x16x32_bf16(Ab[t], b3,  s, 0, 0, 0);
#pragma unroll
            for (int r = 0; r < 4; ++r) {
                if (s[r] > bestv[t][r]) { bestv[t][r] = s[r]; bestc[t][r] = c; }
            }
        }
        __builtin_amdgcn_s_setprio(0);
    }

    // ---- LDS tail: every lane deposits its candidate; no cross-lane ops ----
#pragma unroll
    for (int t = 0; t < 4; ++t) {
#pragma unroll
        for (int r = 0; r < 4; ++r) {
            unsigned code = (unsigned)(codepart * (CT_PER_PART * 16) +
                                       bestc[t][r] * 16 + n);
            unsigned long long packed =
                ((unsigned long long)fkey(bestv[t][r]) << 32) |
                (unsigned long long)(0xFFFFFFFFu - code);
            const int row_loc = (wave * 4 + t) * 16 + quad * 4 + r;
            Lcand[n][row_loc] = packed;
        }
    }
    __syncthreads();

    // thread i owns block-row i: serial max over its 16 candidates, 1 atomic
    {
        const int i = threadIdx.x;                // 0..255 == row_loc
        unsigned long long best = Lcand[0][i];
#pragma unroll
        for (int j = 1; j < 16; ++j) {
            unsigned long long v = Lcand[j][i];
            best = (v > best) ? v : best;
        }
        atomicMax(&part[rowgrp * 256 + i], best);
    }

    // __syncthreads drains vmcnt -> all this block's atomics are complete
    __syncthreads();
    if (threadIdx.x == 0)
        s_done = (atomicAdd(&cnt[rowgrp], 1u) == (unsigned)(CODEPARTS - 1));
    __syncthreads();

    if (s_done) {
        int row = rowgrp * 256 + threadIdx.x;
        unsigned long long v = atomicAdd(&part[row], 0ull);   // coherent read
        out[row] = (int)(0xFFFFFFFFu - (unsigned)(v & 0xFFFFFFFFull));
    }
}

extern "C" void kernel_launch(void* const* d_in, const int* in_sizes, int n_in,
                              void* d_out, int out_size, void* d_ws, size_t ws_size,
                              hipStream_t stream) {
    const float* x  = (const float*)d_in[0];   // [16384, 512]
    const float* P  = (const float*)d_in[1];   // [512, 16]
    const float* CB = (const float*)d_in[2];   // [8192, 16]
    int* out = (int*)d_out;                    // [16384] int32

    char* ws = (char*)d_ws;
    bf16x8* AfragA = (bf16x8*)(ws + WS_OFF_AFA);
    bf16x8* AfragB = (bf16x8*)(ws + WS_OFF_AFB);
    bf16x8* Bhh    = (bf16x8*)(ws + WS_OFF_BHH);
    bf16x8* B31    = (bf16x8*)(ws + WS_OFF_B31);
    unsigned long long* part = (unsigned long long*)(ws + WS_OFF_PART);
    unsigned* cnt  = (unsigned*)(ws + WS_OFF_CNT);

    k_front<<<PROJ_BLOCKS + PREP_BLOCKS, 256, 0, stream>>>(
        x, P, CB, AfragA, AfragB, Bhh, B31, part, cnt);            // 1152 blocks
    k_scan<<<N_ROWGRP * CODEPARTS, 256, 0, stream>>>(
        AfragA, AfragB, Bhh, B31, part, cnt, out);                 // 512 blocks
}